// Round 1
// 5491.084 us; speedup vs baseline: 1.3106x; 1.3106x over previous
//
#include <hip/hip_runtime.h>
#include <math.h>

#define BB 4
#define SS 1000
#define DD 512
#define HH 8
#define HD 64
#define LL 4
#define FFD 2048
#define VV 32000
#define MM (BB*SS)      // 4000
#define QKV_STR 1536    // fused q|k|v row stride

typedef __attribute__((ext_vector_type(8))) short bf16x8;
typedef __attribute__((ext_vector_type(4))) float f32x4;

// ---------------------------------------------------------------------------
// fp32 -> bf16 (RNE) split helpers: f = hi + lo with |err| ~ 2^-17 * |f|
// ---------------------------------------------------------------------------
__device__ __forceinline__ unsigned short f2bf(float f)
{
    unsigned int u = __float_as_uint(f);
    u += 0x7FFFu + ((u >> 16) & 1u);      // round-to-nearest-even
    return (unsigned short)(u >> 16);
}
__device__ __forceinline__ float bf2f(unsigned short h)
{
    return __uint_as_float((unsigned int)h << 16);
}
__device__ __forceinline__ void cvt8(const float* f, unsigned int* hp, unsigned int* lp)
{
#pragma unroll
    for (int j = 0; j < 4; j++) {
        unsigned short h0 = f2bf(f[2 * j]);
        unsigned short h1 = f2bf(f[2 * j + 1]);
        unsigned short l0 = f2bf(f[2 * j] - bf2f(h0));
        unsigned short l1 = f2bf(f[2 * j + 1] - bf2f(h1));
        hp[j] = (unsigned int)h0 | ((unsigned int)h1 << 16);
        lp[j] = (unsigned int)l0 | ((unsigned int)l1 << 16);
    }
}

// ---------------------------------------------------------------------------
// Embedding + positional encoding
// ---------------------------------------------------------------------------
__global__ __launch_bounds__(256) void embed_pe_kernel(
    const int* __restrict__ tokens, const float* __restrict__ emb,
    float* __restrict__ x)
{
    int idx = blockIdx.x * 256 + threadIdx.x;      // < B*S*D
    int d  = idx & (DD - 1);
    int bs = idx >> 9;
    int s  = bs % SS;
    int tok = tokens[bs];
    float i2 = (float)(d & ~1);
    float dv = expf(i2 * (-9.210340371976184f / (float)DD));
    float ang = (float)s * dv;
    float pe = (d & 1) ? cosf(ang) : sinf(ang);
    x[idx] = emb[(size_t)tok * DD + d] + pe;
}

// ---------------------------------------------------------------------------
// Split-bf16 MFMA GEMM core. One 128x128 C-tile per block, 256 threads
// (4 waves, each 64x64 via 4x4 fragments of 16x16x32 MFMA).
// C[M, ldc][ccol..+128) = A[M,K] @ W[K, ldw][wcol..+128) + bias, opt ReLU.
// fp32 operands split hi/lo in LDS; 3 MFMAs (hh, hl, lh) per fragment pair.
// LDS rows padded to 40 bf16 (80 B) -> worst 2-way bank alias (free).
// ---------------------------------------------------------------------------
#define BKP 40

__device__ __forceinline__ void gemm_core(
    const float* __restrict__ A, const float* __restrict__ W, int ldw, int wcol,
    const float* __restrict__ bias, float* __restrict__ C, int ldc, int ccol,
    int M, int K, int relu, int bm)
{
    __shared__ unsigned short Ah[128][BKP];
    __shared__ unsigned short Al[128][BKP];
    __shared__ unsigned short Bh[128][BKP];
    __shared__ unsigned short Bl[128][BKP];

    const int tid  = threadIdx.x;
    const int lane = tid & 63;
    const int wid  = tid >> 6;
    const int wm   = (wid >> 1) << 6;       // 0 / 64
    const int wn   = (wid & 1) << 6;        // 0 / 64
    const int fr   = lane & 15;             // A row / B col within fragment
    const int ko   = (lane >> 4) << 3;      // k offset 0/8/16/24

    // staging coordinates
    const int am  = tid >> 2;               // A row (unit 0), +64 for unit 1
    const int aks = (tid & 3) << 3;         // A k-octet
    const int bn  = tid & 63;               // B col (unit 0), +64 for unit 1
    const int bkk = (tid >> 6) << 3;        // B k-octet

    f32x4 acc[4][4];
#pragma unroll
    for (int i = 0; i < 4; i++)
#pragma unroll
        for (int j = 0; j < 4; j++)
            acc[i][j] = (f32x4){0.f, 0.f, 0.f, 0.f};

    for (int k0 = 0; k0 < K; k0 += 32) {
        // ---- stage A tile (128 x 32), convert to hi/lo bf16 -------------
#pragma unroll
        for (int u = 0; u < 2; u++) {
            const int m  = am + (u << 6);
            const int gm = bm + m;
            float fv[8];
            if (gm < M) {
                const float* ap = &A[(size_t)gm * K + k0 + aks];
                float4 x0 = *(const float4*)ap;
                float4 x1 = *(const float4*)(ap + 4);
                fv[0] = x0.x; fv[1] = x0.y; fv[2] = x0.z; fv[3] = x0.w;
                fv[4] = x1.x; fv[5] = x1.y; fv[6] = x1.z; fv[7] = x1.w;
            } else {
#pragma unroll
                for (int j = 0; j < 8; j++) fv[j] = 0.f;
            }
            unsigned int hp[4], lp[4];
            cvt8(fv, hp, lp);
            *(uint4*)&Ah[m][aks] = make_uint4(hp[0], hp[1], hp[2], hp[3]);
            *(uint4*)&Al[m][aks] = make_uint4(lp[0], lp[1], lp[2], lp[3]);
        }
        // ---- stage B tile (32 x 128) transposed to [n][k] ---------------
#pragma unroll
        for (int u = 0; u < 2; u++) {
            const int n = bn + (u << 6);
            const float* wp = &W[(size_t)(k0 + bkk) * ldw + wcol + n];
            float fv[8];
#pragma unroll
            for (int i = 0; i < 8; i++) fv[i] = wp[(size_t)i * ldw];
            unsigned int hp[4], lp[4];
            cvt8(fv, hp, lp);
            *(uint4*)&Bh[n][bkk] = make_uint4(hp[0], hp[1], hp[2], hp[3]);
            *(uint4*)&Bl[n][bkk] = make_uint4(lp[0], lp[1], lp[2], lp[3]);
        }
        __syncthreads();

        // ---- fragments + 3-term MFMA ------------------------------------
        bf16x8 ah[4], al[4], bh[4], bl[4];
#pragma unroll
        for (int i = 0; i < 4; i++) {
            ah[i] = *(const bf16x8*)&Ah[wm + i * 16 + fr][ko];
            al[i] = *(const bf16x8*)&Al[wm + i * 16 + fr][ko];
        }
#pragma unroll
        for (int j = 0; j < 4; j++) {
            bh[j] = *(const bf16x8*)&Bh[wn + j * 16 + fr][ko];
            bl[j] = *(const bf16x8*)&Bl[wn + j * 16 + fr][ko];
        }
#pragma unroll
        for (int i = 0; i < 4; i++)
#pragma unroll
            for (int j = 0; j < 4; j++) {
                acc[i][j] = __builtin_amdgcn_mfma_f32_16x16x32_bf16(ah[i], bh[j], acc[i][j], 0, 0, 0);
                acc[i][j] = __builtin_amdgcn_mfma_f32_16x16x32_bf16(ah[i], bl[j], acc[i][j], 0, 0, 0);
                acc[i][j] = __builtin_amdgcn_mfma_f32_16x16x32_bf16(al[i], bh[j], acc[i][j], 0, 0, 0);
            }
        __syncthreads();
    }

    // ---- epilogue: D[row=(lane>>4)*4+r][col=lane&15] (verified mapping) --
    const int cr = (lane >> 4) << 2;
    const int cc = lane & 15;
#pragma unroll
    for (int j = 0; j < 4; j++) {
        const int lc  = wn + j * 16 + cc;
        const float bv = bias[wcol + lc];
        const int col = ccol + lc;
#pragma unroll
        for (int i = 0; i < 4; i++) {
            f32x4 a = acc[i][j];
#pragma unroll
            for (int r = 0; r < 4; r++) {
                const int row = bm + wm + i * 16 + cr + r;
                if (row < M) {
                    float v = a[r] + bv;
                    if (relu) v = fmaxf(v, 0.f);
                    C[(size_t)row * ldc + col] = v;
                }
            }
        }
    }
}

__global__ __launch_bounds__(256) void gemm_mfma_kernel(
    const float* __restrict__ A, const float* __restrict__ W,
    const float* __restrict__ bias, float* __restrict__ C,
    int M, int N, int K, int relu)
{
    const int bm   = blockIdx.y * 128;
    const int wcol = blockIdx.x * 128;
    gemm_core(A, W, N, wcol, bias, C, N, wcol, M, K, relu, bm);
}

// Fused QKV: grid.x = 12 (3 matrices x 4 col-blocks), output [M][1536].
__global__ __launch_bounds__(256) void gemm_qkv_kernel(
    const float* __restrict__ A,
    const float* __restrict__ wq, const float* __restrict__ wk, const float* __restrict__ wv,
    const float* __restrict__ bq, const float* __restrict__ bk, const float* __restrict__ bv,
    float* __restrict__ qkv, int M)
{
    const int bm   = blockIdx.y * 128;
    const int bx   = blockIdx.x;
    const int sel  = bx >> 2;
    const int wcol = (bx & 3) << 7;
    const int ccol = bx << 7;
    const float* W  = (sel == 0) ? wq : (sel == 1) ? wk : wv;
    const float* bi = (sel == 0) ? bq : (sel == 1) ? bk : bv;
    gemm_core(A, W, DD, wcol, bi, qkv, QKV_STR, ccol, M, DD, 0, bm);
}

// ---------------------------------------------------------------------------
// Attention over fused qkv buffer [M][1536] (q|k|v). One block per
// (b, h, 8-row q tile). ctx out is [M][512].
// ---------------------------------------------------------------------------
#define SC_PITCH 1028
__global__ __launch_bounds__(256) void attention_kernel(
    const float* __restrict__ qkv, float* __restrict__ ctx)
{
    const int blk = blockIdx.x;
    const int qblk = blk % (SS / 8);
    const int bh = blk / (SS / 8);
    const int h = bh % HH;
    const int b = bh / HH;
    const int s0 = qblk * 8;
    const int tid = threadIdx.x;

    __shared__ float sc[8][SC_PITCH];
    __shared__ float row_sum[8];

    // ---- phase 1: scores -------------------------------------------------
    {
        const int qi = tid & 7;
        const float* qrow = qkv + (size_t)(b * SS + s0 + qi) * QKV_STR + h * HD;
        float4 qreg[16];
#pragma unroll
        for (int j = 0; j < 16; j++) qreg[j] = ((const float4*)qrow)[j];

        for (int idx = tid; idx < 8 * SS; idx += 256) {
            const int kj = idx >> 3;
            const float* krow = qkv + (size_t)(b * SS + kj) * QKV_STR + DD + h * HD;
            float acc = 0.f;
#pragma unroll
            for (int j = 0; j < 16; j++) {
                float4 kv = ((const float4*)krow)[j];
                acc = fmaf(qreg[j].x, kv.x, acc);
                acc = fmaf(qreg[j].y, kv.y, acc);
                acc = fmaf(qreg[j].z, kv.z, acc);
                acc = fmaf(qreg[j].w, kv.w, acc);
            }
            sc[qi][kj] = acc * 0.125f;
        }
    }
    __syncthreads();

    // ---- phase 2: softmax numerators ------------------------------------
    {
        const int w = tid >> 6;
        const int lane = tid & 63;
        for (int r = w; r < 8; r += 4) {
            float mx = -1e30f;
            for (int j = lane; j < SS; j += 64) mx = fmaxf(mx, sc[r][j]);
#pragma unroll
            for (int off = 32; off > 0; off >>= 1)
                mx = fmaxf(mx, __shfl_xor(mx, off));
            float sum = 0.f;
            for (int j = lane; j < SS; j += 64) {
                float e = expf(sc[r][j] - mx);
                sc[r][j] = e;
                sum += e;
            }
#pragma unroll
            for (int off = 32; off > 0; off >>= 1)
                sum += __shfl_xor(sum, off);
            if (lane == 0) row_sum[r] = sum;
        }
    }
    __syncthreads();

    // ---- phase 3: ctx = (attn @ v) / sum ---------------------------------
    {
        const int d = tid & 63;
        const int qp = tid >> 6;
        float acc0 = 0.f, acc1 = 0.f;
        for (int kj0 = 0; kj0 < SS / 4; kj0++) {
            float4 s0v = *(const float4*)&sc[qp][kj0 * 4];
            float4 s1v = *(const float4*)&sc[qp + 4][kj0 * 4];
            const float* vr = qkv + (size_t)(b * SS + kj0 * 4) * QKV_STR + 2 * DD + h * HD + d;
            float v0 = vr[0];
            float v1 = vr[QKV_STR];
            float v2 = vr[2 * QKV_STR];
            float v3 = vr[3 * QKV_STR];
            acc0 = fmaf(s0v.x, v0, acc0);
            acc0 = fmaf(s0v.y, v1, acc0);
            acc0 = fmaf(s0v.z, v2, acc0);
            acc0 = fmaf(s0v.w, v3, acc0);
            acc1 = fmaf(s1v.x, v0, acc1);
            acc1 = fmaf(s1v.y, v1, acc1);
            acc1 = fmaf(s1v.z, v2, acc1);
            acc1 = fmaf(s1v.w, v3, acc1);
        }
        float inv0 = 1.f / row_sum[qp];
        float inv1 = 1.f / row_sum[qp + 4];
        ctx[((size_t)(b * SS + s0 + qp) * DD) + h * HD + d] = acc0 * inv0;
        ctx[((size_t)(b * SS + s0 + qp + 4) * DD) + h * HD + d] = acc1 * inv1;
    }
}

// ---------------------------------------------------------------------------
// x = LayerNorm(x + res) * g + b   (in place). One block (128 thr) / row.
// ---------------------------------------------------------------------------
__global__ __launch_bounds__(128) void add_ln_kernel(
    float* __restrict__ x, const float* __restrict__ res,
    const float* __restrict__ g, const float* __restrict__ bta)
{
    const int row = blockIdx.x;
    const int tid = threadIdx.x;
    float* xr = x + (size_t)row * DD;
    const float* rr = res + (size_t)row * DD;

    float4 xv = ((const float4*)xr)[tid];
    float4 rv = ((const float4*)rr)[tid];
    xv.x += rv.x; xv.y += rv.y; xv.z += rv.z; xv.w += rv.w;

    __shared__ float red1[2];
    __shared__ float red2[2];
    const int lane = tid & 63;
    const int w = tid >> 6;

    float s = xv.x + xv.y + xv.z + xv.w;
#pragma unroll
    for (int off = 32; off > 0; off >>= 1) s += __shfl_xor(s, off);
    if (lane == 0) red1[w] = s;
    __syncthreads();
    const float mean = (red1[0] + red1[1]) * (1.f / (float)DD);

    float d0 = xv.x - mean, d1 = xv.y - mean, d2 = xv.z - mean, d3 = xv.w - mean;
    float sq = d0 * d0 + d1 * d1 + d2 * d2 + d3 * d3;
#pragma unroll
    for (int off = 32; off > 0; off >>= 1) sq += __shfl_xor(sq, off);
    if (lane == 0) red2[w] = sq;
    __syncthreads();
    const float inv = 1.f / sqrtf((red2[0] + red2[1]) * (1.f / (float)DD) + 1e-5f);

    float4 gv = ((const float4*)g)[tid];
    float4 bv = ((const float4*)bta)[tid];
    float4 o;
    o.x = d0 * inv * gv.x + bv.x;
    o.y = d1 * inv * gv.y + bv.y;
    o.z = d2 * inv * gv.z + bv.z;
    o.w = d3 * inv * gv.w + bv.w;
    ((float4*)xr)[tid] = o;
}

// ---------------------------------------------------------------------------
// Row softmax over V=32000, in place. One block (256 thr) per row.
// ---------------------------------------------------------------------------
__global__ __launch_bounds__(256) void softmax_kernel(float* __restrict__ out)
{
    const int row = blockIdx.x;
    float* p = out + (size_t)row * VV;
    const int tid = threadIdx.x;

    float m = -1e30f, s = 0.f;
    for (int j = tid * 4; j < VV; j += 1024) {
        float4 c = *(const float4*)&p[j];
        float lm = fmaxf(fmaxf(c.x, c.y), fmaxf(c.z, c.w));
        if (lm > m) { s *= expf(m - lm); m = lm; }
        s += expf(c.x - m) + expf(c.y - m) + expf(c.z - m) + expf(c.w - m);
    }
#pragma unroll
    for (int off = 32; off > 0; off >>= 1) {
        float mo = __shfl_xor(m, off);
        float so = __shfl_xor(s, off);
        float nm = fmaxf(m, mo);
        s = s * expf(m - nm) + so * expf(mo - nm);
        m = nm;
    }
    __shared__ float ms[4], ss2[4];
    const int lane = tid & 63;
    const int w = tid >> 6;
    if (lane == 0) { ms[w] = m; ss2[w] = s; }
    __syncthreads();
    float fm = fmaxf(fmaxf(ms[0], ms[1]), fmaxf(ms[2], ms[3]));
    float fs = ss2[0] * expf(ms[0] - fm) + ss2[1] * expf(ms[1] - fm) +
               ss2[2] * expf(ms[2] - fm) + ss2[3] * expf(ms[3] - fm);
    const float inv = 1.f / fs;
    for (int j = tid * 4; j < VV; j += 1024) {
        float4 c = *(const float4*)&p[j];
        c.x = expf(c.x - fm) * inv;
        c.y = expf(c.y - fm) * inv;
        c.z = expf(c.z - fm) * inv;
        c.w = expf(c.w - fm) * inv;
        *(float4*)&p[j] = c;
    }
}

// ---------------------------------------------------------------------------
static inline void launch_gemm(const float* A, const float* W, const float* bias,
                               float* C, int M, int N, int K, int relu,
                               hipStream_t st)
{
    dim3 grid(N / 128, (M + 127) / 128);
    gemm_mfma_kernel<<<grid, 256, 0, st>>>(A, W, bias, C, M, N, K, relu);
}

extern "C" void kernel_launch(void* const* d_in, const int* in_sizes, int n_in,
                              void* d_out, int out_size, void* d_ws, size_t ws_size,
                              hipStream_t stream)
{
    const int*   tokens = (const int*)  d_in[0];
    const float* emb    = (const float*)d_in[1];
    const float* wq     = (const float*)d_in[2];
    const float* bq     = (const float*)d_in[3];
    const float* wk     = (const float*)d_in[4];
    const float* bk     = (const float*)d_in[5];
    const float* wv     = (const float*)d_in[6];
    const float* bv     = (const float*)d_in[7];
    const float* wo     = (const float*)d_in[8];
    const float* bo     = (const float*)d_in[9];
    const float* ln1g   = (const float*)d_in[10];
    const float* ln1b   = (const float*)d_in[11];
    const float* w1     = (const float*)d_in[12];
    const float* b1     = (const float*)d_in[13];
    const float* w2     = (const float*)d_in[14];
    const float* b2     = (const float*)d_in[15];
    const float* ln2g   = (const float*)d_in[16];
    const float* ln2b   = (const float*)d_in[17];
    const float* fcw    = (const float*)d_in[18];
    const float* fcb    = (const float*)d_in[19];
    float* out = (float*)d_out;

    const size_t XN = (size_t)MM * DD;        // 2,048,000
    float* x    = (float*)d_ws;
    float* qkv  = x   + XN;                   // [M][1536] fused
    float* ctx  = qkv + 3 * XN;
    float* attn = ctx + XN;
    // FFN hidden parked in tail of d_out (dead before final GEMM writes).
    float* hbuf = out + ((size_t)MM * VV - (size_t)MM * FFD);

    embed_pe_kernel<<<(MM * DD) / 256, 256, 0, stream>>>(tokens, emb, x);

    for (int l = 0; l < LL; l++) {
        const size_t wo2 = (size_t)l * DD * DD;
        gemm_qkv_kernel<<<dim3(12, (MM + 127) / 128), 256, 0, stream>>>(
            x, wq + wo2, wk + wo2, wv + wo2,
            bq + l * DD, bk + l * DD, bv + l * DD, qkv, MM);
        attention_kernel<<<BB * HH * (SS / 8), 256, 0, stream>>>(qkv, ctx);
        launch_gemm(ctx, wo + wo2, bo + l * DD, attn, MM, DD, DD, 0, stream);
        add_ln_kernel<<<MM, 128, 0, stream>>>(x, attn, ln1g + l * DD, ln1b + l * DD);
        launch_gemm(x, w1 + (size_t)l * DD * FFD, b1 + l * FFD, hbuf, MM, FFD, DD, 1, stream);
        launch_gemm(hbuf, w2 + (size_t)l * FFD * DD, b2 + l * DD, attn, MM, DD, FFD, 0, stream);
        add_ln_kernel<<<MM, 128, 0, stream>>>(x, attn, ln2g + l * DD, ln2b + l * DD);
    }

    launch_gemm(x, fcw, fcb, out, MM, VV, DD, 0, stream);
    softmax_kernel<<<MM, 256, 0, stream>>>(out);
}

// Round 3
// 2942.078 us; speedup vs baseline: 2.4461x; 1.8664x over previous
//
#include <hip/hip_runtime.h>
#include <math.h>

#define BB 4
#define SS 1000
#define DD 512
#define HH 8
#define HD 64
#define LL 4
#define FFD 2048
#define VV 32000
#define MM (BB*SS)      // 4000
#define QKV_STR 1536    // fused q|k|v row stride

typedef __attribute__((ext_vector_type(8))) short bf16x8;
typedef __attribute__((ext_vector_type(4))) short bf16x4;
typedef __attribute__((ext_vector_type(4))) float f32x4;

// ---------------------------------------------------------------------------
// fp32 -> bf16 (RNE) split helpers: f = hi + lo with |err| ~ 2^-17 * |f|
// ---------------------------------------------------------------------------
__device__ __forceinline__ unsigned short f2bf(float f)
{
    unsigned int u = __float_as_uint(f);
    u += 0x7FFFu + ((u >> 16) & 1u);      // round-to-nearest-even
    return (unsigned short)(u >> 16);
}
__device__ __forceinline__ float bf2f(unsigned short h)
{
    return __uint_as_float((unsigned int)h << 16);
}
__device__ __forceinline__ void cvt8(const float* f, unsigned int* hp, unsigned int* lp)
{
#pragma unroll
    for (int j = 0; j < 4; j++) {
        unsigned short h0 = f2bf(f[2 * j]);
        unsigned short h1 = f2bf(f[2 * j + 1]);
        unsigned short l0 = f2bf(f[2 * j] - bf2f(h0));
        unsigned short l1 = f2bf(f[2 * j + 1] - bf2f(h1));
        hp[j] = (unsigned int)h0 | ((unsigned int)h1 << 16);
        lp[j] = (unsigned int)l0 | ((unsigned int)l1 << 16);
    }
}
__device__ __forceinline__ void split8(const float* f, bf16x8& h8, bf16x8& l8)
{
#pragma unroll
    for (int j = 0; j < 8; j++) {
        unsigned short h = f2bf(f[j]);
        unsigned short l = f2bf(f[j] - bf2f(h));
        h8[j] = (short)h;
        l8[j] = (short)l;
    }
}

// ---------------------------------------------------------------------------
// Embedding + positional encoding
// ---------------------------------------------------------------------------
__global__ __launch_bounds__(256) void embed_pe_kernel(
    const int* __restrict__ tokens, const float* __restrict__ emb,
    float* __restrict__ x)
{
    int idx = blockIdx.x * 256 + threadIdx.x;      // < B*S*D
    int d  = idx & (DD - 1);
    int bs = idx >> 9;
    int s  = bs % SS;
    int tok = tokens[bs];
    float i2 = (float)(d & ~1);
    float dv = expf(i2 * (-9.210340371976184f / (float)DD));
    float ang = (float)s * dv;
    float pe = (d & 1) ? cosf(ang) : sinf(ang);
    x[idx] = emb[(size_t)tok * DD + d] + pe;
}

// ---------------------------------------------------------------------------
// Split-bf16 MFMA GEMM core.
// ---------------------------------------------------------------------------
#define BKP 40

__device__ __forceinline__ void gemm_core(
    const float* __restrict__ A, const float* __restrict__ W, int ldw, int wcol,
    const float* __restrict__ bias, float* __restrict__ C, int ldc, int ccol,
    int M, int K, int relu, int bm)
{
    __shared__ unsigned short Ah[128][BKP];
    __shared__ unsigned short Al[128][BKP];
    __shared__ unsigned short Bh[128][BKP];
    __shared__ unsigned short Bl[128][BKP];

    const int tid  = threadIdx.x;
    const int lane = tid & 63;
    const int wid  = tid >> 6;
    const int wm   = (wid >> 1) << 6;
    const int wn   = (wid & 1) << 6;
    const int fr   = lane & 15;
    const int ko   = (lane >> 4) << 3;

    const int am  = tid >> 2;
    const int aks = (tid & 3) << 3;
    const int bn  = tid & 63;
    const int bkk = (tid >> 6) << 3;

    f32x4 acc[4][4];
#pragma unroll
    for (int i = 0; i < 4; i++)
#pragma unroll
        for (int j = 0; j < 4; j++)
            acc[i][j] = (f32x4){0.f, 0.f, 0.f, 0.f};

    for (int k0 = 0; k0 < K; k0 += 32) {
#pragma unroll
        for (int u = 0; u < 2; u++) {
            const int m  = am + (u << 6);
            const int gm = bm + m;
            float fv[8];
            if (gm < M) {
                const float* ap = &A[(size_t)gm * K + k0 + aks];
                float4 x0 = *(const float4*)ap;
                float4 x1 = *(const float4*)(ap + 4);
                fv[0] = x0.x; fv[1] = x0.y; fv[2] = x0.z; fv[3] = x0.w;
                fv[4] = x1.x; fv[5] = x1.y; fv[6] = x1.z; fv[7] = x1.w;
            } else {
#pragma unroll
                for (int j = 0; j < 8; j++) fv[j] = 0.f;
            }
            unsigned int hp[4], lp[4];
            cvt8(fv, hp, lp);
            *(uint4*)&Ah[m][aks] = make_uint4(hp[0], hp[1], hp[2], hp[3]);
            *(uint4*)&Al[m][aks] = make_uint4(lp[0], lp[1], lp[2], lp[3]);
        }
#pragma unroll
        for (int u = 0; u < 2; u++) {
            const int n = bn + (u << 6);
            const float* wp = &W[(size_t)(k0 + bkk) * ldw + wcol + n];
            float fv[8];
#pragma unroll
            for (int i = 0; i < 8; i++) fv[i] = wp[(size_t)i * ldw];
            unsigned int hp[4], lp[4];
            cvt8(fv, hp, lp);
            *(uint4*)&Bh[n][bkk] = make_uint4(hp[0], hp[1], hp[2], hp[3]);
            *(uint4*)&Bl[n][bkk] = make_uint4(lp[0], lp[1], lp[2], lp[3]);
        }
        __syncthreads();

        bf16x8 ah[4], al[4], bh[4], bl[4];
#pragma unroll
        for (int i = 0; i < 4; i++) {
            ah[i] = *(const bf16x8*)&Ah[wm + i * 16 + fr][ko];
            al[i] = *(const bf16x8*)&Al[wm + i * 16 + fr][ko];
        }
#pragma unroll
        for (int j = 0; j < 4; j++) {
            bh[j] = *(const bf16x8*)&Bh[wn + j * 16 + fr][ko];
            bl[j] = *(const bf16x8*)&Bl[wn + j * 16 + fr][ko];
        }
#pragma unroll
        for (int i = 0; i < 4; i++)
#pragma unroll
            for (int j = 0; j < 4; j++) {
                acc[i][j] = __builtin_amdgcn_mfma_f32_16x16x32_bf16(ah[i], bh[j], acc[i][j], 0, 0, 0);
                acc[i][j] = __builtin_amdgcn_mfma_f32_16x16x32_bf16(ah[i], bl[j], acc[i][j], 0, 0, 0);
                acc[i][j] = __builtin_amdgcn_mfma_f32_16x16x32_bf16(al[i], bh[j], acc[i][j], 0, 0, 0);
            }
        __syncthreads();
    }

    const int cr = (lane >> 4) << 2;
    const int cc = lane & 15;
#pragma unroll
    for (int j = 0; j < 4; j++) {
        const int lc  = wn + j * 16 + cc;
        const float bv = bias[wcol + lc];
        const int col = ccol + lc;
#pragma unroll
        for (int i = 0; i < 4; i++) {
            f32x4 a = acc[i][j];
#pragma unroll
            for (int r = 0; r < 4; r++) {
                const int row = bm + wm + i * 16 + cr + r;
                if (row < M) {
                    float v = a[r] + bv;
                    if (relu) v = fmaxf(v, 0.f);
                    C[(size_t)row * ldc + col] = v;
                }
            }
        }
    }
}

__global__ __launch_bounds__(256) void gemm_mfma_kernel(
    const float* __restrict__ A, const float* __restrict__ W,
    const float* __restrict__ bias, float* __restrict__ C,
    int M, int N, int K, int relu)
{
    const int bm   = blockIdx.y * 128;
    const int wcol = blockIdx.x * 128;
    gemm_core(A, W, N, wcol, bias, C, N, wcol, M, K, relu, bm);
}

__global__ __launch_bounds__(256) void gemm_qkv_kernel(
    const float* __restrict__ A,
    const float* __restrict__ wq, const float* __restrict__ wk, const float* __restrict__ wv,
    const float* __restrict__ bq, const float* __restrict__ bk, const float* __restrict__ bv,
    float* __restrict__ qkv, int M)
{
    const int bm   = blockIdx.y * 128;
    const int bx   = blockIdx.x;
    const int sel  = bx >> 2;
    const int wcol = (bx & 3) << 7;
    const int ccol = bx << 7;
    const float* W  = (sel == 0) ? wq : (sel == 1) ? wk : wv;
    const float* bi = (sel == 0) ? bq : (sel == 1) ? bk : bv;
    gemm_core(A, W, DD, wcol, bi, qkv, QKV_STR, ccol, M, DD, 0, bm);
}

// ---------------------------------------------------------------------------
// Flash-style MFMA attention (swapped operands).
// Block: 512 thr = 8 waves; wave w owns 16 q-rows (qi = q0 + w*16 + lane&15).
// Per KV tile (64 rows): stage K [kj][d] + V^T [d][kj] as bf16 hi/lo in LDS.
//   S^T = K·Q^T  (A=K-frag, B=Q-frag in regs)    -> lane-local q-row softmax
//   O^T += V^T·P^T (A=Vt-frag, B=P from S^T C-regs, no cross-lane movement)
// hi/lo split on both matmuls: 3 MFMAs per logical fragment product.
// ---------------------------------------------------------------------------
#define QT 128
#define KVT 64
#define KP 72      // K row pitch (ushorts)
#define VP 72      // Vt row pitch (ushorts)

__device__ __forceinline__ bf16x8 ld_pair(const unsigned short* p0,
                                          const unsigned short* p1)
{
    union { bf16x8 v; bf16x4 q[2]; } u;
    u.q[0] = *(const bf16x4*)p0;
    u.q[1] = *(const bf16x4*)p1;
    return u.v;
}

__global__ __launch_bounds__(512) void attention_kernel(
    const float* __restrict__ qkv, float* __restrict__ ctx)
{
    __shared__ __align__(16) unsigned short Kh[KVT][KP];
    __shared__ __align__(16) unsigned short Kl[KVT][KP];
    __shared__ __align__(16) unsigned short Vth[HD][VP];
    __shared__ __align__(16) unsigned short Vtl[HD][VP];

    const int tid  = threadIdx.x;
    const int lane = tid & 63;
    const int w    = tid >> 6;        // wave 0..7
    const int r16  = lane & 15;       // qi within wave / frag row
    const int g    = lane >> 4;       // 0..3

    const int nqt = (SS + QT - 1) / QT;          // 8
    const int qt  = blockIdx.x % nqt;
    const int bh  = blockIdx.x / nqt;
    const int h   = bh % HH;
    const int b   = bh / HH;
    const int q0  = qt * QT;

    const size_t base = (size_t)b * SS * QKV_STR + (size_t)h * HD;

    // ---- Q fragments in registers (pre-scaled by 1/8) --------------------
    const int qrow = q0 + w * 16 + r16;
    const int qr   = qrow < SS ? qrow : SS - 1;
    const float* qp = qkv + base + (size_t)qr * QKV_STR;
    bf16x8 qh[2], ql[2];
#pragma unroll
    for (int c = 0; c < 2; c++) {
        float4 qa = *(const float4*)&qp[c * 32 + g * 4];
        float4 qb = *(const float4*)&qp[c * 32 + 16 + g * 4];
        float fv[8] = {qa.x * 0.125f, qa.y * 0.125f, qa.z * 0.125f, qa.w * 0.125f,
                       qb.x * 0.125f, qb.y * 0.125f, qb.z * 0.125f, qb.w * 0.125f};
        split8(fv, qh[c], ql[c]);
    }

    f32x4 oacc[4];
#pragma unroll
    for (int f = 0; f < 4; f++) oacc[f] = (f32x4){0.f, 0.f, 0.f, 0.f};
    float mrow = -1e30f, lrow = 0.f;

    const int ntiles = (SS + KVT - 1) / KVT;     // 16
    for (int t = 0; t < ntiles; t++) {
        const int kv0 = t * KVT;
        __syncthreads();
        // ---- stage K tile: [kj][d] hi/lo ---------------------------------
        {
            const int kj   = tid >> 3;
            const int dblk = (tid & 7) * 8;
            float fv[8];
            const int krow = kv0 + kj;
            if (krow < SS) {
                const float* kp = qkv + base + (size_t)krow * QKV_STR + DD;
                float4 a0 = *(const float4*)&kp[dblk];
                float4 a1 = *(const float4*)&kp[dblk + 4];
                fv[0] = a0.x; fv[1] = a0.y; fv[2] = a0.z; fv[3] = a0.w;
                fv[4] = a1.x; fv[5] = a1.y; fv[6] = a1.z; fv[7] = a1.w;
            } else {
#pragma unroll
                for (int j = 0; j < 8; j++) fv[j] = 0.f;
            }
            bf16x8 h8, l8;
            split8(fv, h8, l8);
            *(bf16x8*)&Kh[kj][dblk] = h8;
            *(bf16x8*)&Kl[kj][dblk] = l8;
        }
        // ---- stage V tile transposed: Vt[d][kj] hi/lo --------------------
        {
            const int kj = tid & 63;
            const int d0 = (tid >> 6) * 8;
            float fv[8];
            const int vrow = kv0 + kj;
            if (vrow < SS) {
                const float* vp = qkv + base + (size_t)vrow * QKV_STR + 2 * DD;
                float4 a0 = *(const float4*)&vp[d0];
                float4 a1 = *(const float4*)&vp[d0 + 4];
                fv[0] = a0.x; fv[1] = a0.y; fv[2] = a0.z; fv[3] = a0.w;
                fv[4] = a1.x; fv[5] = a1.y; fv[6] = a1.z; fv[7] = a1.w;
            } else {
#pragma unroll
                for (int j = 0; j < 8; j++) fv[j] = 0.f;
            }
#pragma unroll
            for (int i = 0; i < 8; i++) {
                unsigned short hh = f2bf(fv[i]);
                unsigned short ll = f2bf(fv[i] - bf2f(hh));
                Vth[d0 + i][kj] = hh;
                Vtl[d0 + i][kj] = ll;
            }
        }
        __syncthreads();

        // ---- S^T = K·Q^T --------------------------------------------------
        f32x4 sac[4];
#pragma unroll
        for (int f = 0; f < 4; f++) sac[f] = (f32x4){0.f, 0.f, 0.f, 0.f};
#pragma unroll
        for (int f = 0; f < 4; f++) {
            const int ar = f * 16 + r16;
#pragma unroll
            for (int c = 0; c < 2; c++) {
                bf16x8 ah = ld_pair(&Kh[ar][c * 32 + g * 4], &Kh[ar][c * 32 + 16 + g * 4]);
                bf16x8 al = ld_pair(&Kl[ar][c * 32 + g * 4], &Kl[ar][c * 32 + 16 + g * 4]);
                sac[f] = __builtin_amdgcn_mfma_f32_16x16x32_bf16(ah, qh[c], sac[f], 0, 0, 0);
                sac[f] = __builtin_amdgcn_mfma_f32_16x16x32_bf16(ah, ql[c], sac[f], 0, 0, 0);
                sac[f] = __builtin_amdgcn_mfma_f32_16x16x32_bf16(al, qh[c], sac[f], 0, 0, 0);
            }
        }
        // mask tail kj
        if (kv0 + KVT > SS) {
#pragma unroll
            for (int f = 0; f < 4; f++)
#pragma unroll
                for (int rr = 0; rr < 4; rr++)
                    if (kv0 + f * 16 + g * 4 + rr >= SS) sac[f][rr] = -1e30f;
        }

        // ---- online softmax (per qi = lane&15, replicated over g) --------
        float tmax = -1e30f;
#pragma unroll
        for (int f = 0; f < 4; f++)
#pragma unroll
            for (int rr = 0; rr < 4; rr++) tmax = fmaxf(tmax, sac[f][rr]);
        tmax = fmaxf(tmax, __shfl_xor(tmax, 16));
        tmax = fmaxf(tmax, __shfl_xor(tmax, 32));
        const float mnew = fmaxf(mrow, tmax);
        const float scal = __expf(mrow - mnew);
        mrow = mnew;
        float tsum = 0.f;
#pragma unroll
        for (int f = 0; f < 4; f++)
#pragma unroll
            for (int rr = 0; rr < 4; rr++) {
                float e = __expf(sac[f][rr] - mnew);
                sac[f][rr] = e;
                tsum += e;
            }
        tsum += __shfl_xor(tsum, 16);
        tsum += __shfl_xor(tsum, 32);
        lrow = lrow * scal + tsum;
#pragma unroll
        for (int f = 0; f < 4; f++) {
            oacc[f][0] *= scal; oacc[f][1] *= scal;
            oacc[f][2] *= scal; oacc[f][3] *= scal;
        }

        // ---- P -> bf16 hi/lo B-fragments (pure reg, concat C-regs) -------
        bf16x8 ph[2], pl[2];
#pragma unroll
        for (int c = 0; c < 2; c++) {
            float pv[8] = {sac[2 * c][0], sac[2 * c][1], sac[2 * c][2], sac[2 * c][3],
                           sac[2 * c + 1][0], sac[2 * c + 1][1], sac[2 * c + 1][2], sac[2 * c + 1][3]};
            split8(pv, ph[c], pl[c]);
        }

        // ---- O^T += V^T · P^T --------------------------------------------
#pragma unroll
        for (int f = 0; f < 4; f++) {
            const int ar = f * 16 + r16;
#pragma unroll
            for (int c = 0; c < 2; c++) {
                bf16x8 vh = ld_pair(&Vth[ar][c * 32 + g * 4], &Vth[ar][c * 32 + 16 + g * 4]);
                bf16x8 vl = ld_pair(&Vtl[ar][c * 32 + g * 4], &Vtl[ar][c * 32 + 16 + g * 4]);
                oacc[f] = __builtin_amdgcn_mfma_f32_16x16x32_bf16(vh, ph[c], oacc[f], 0, 0, 0);
                oacc[f] = __builtin_amdgcn_mfma_f32_16x16x32_bf16(vh, pl[c], oacc[f], 0, 0, 0);
                oacc[f] = __builtin_amdgcn_mfma_f32_16x16x32_bf16(vl, ph[c], oacc[f], 0, 0, 0);
            }
        }
    }

    // ---- epilogue: ctx[qi][d] = O^T / l ----------------------------------
    if (qrow < SS) {
        const float inv = 1.f / lrow;
        float* cp = ctx + ((size_t)b * SS + qrow) * DD + (size_t)h * HD;
#pragma unroll
        for (int f = 0; f < 4; f++) {
            float4 o;
            o.x = oacc[f][0] * inv;
            o.y = oacc[f][1] * inv;
            o.z = oacc[f][2] * inv;
            o.w = oacc[f][3] * inv;
            *(float4*)&cp[f * 16 + g * 4] = o;
        }
    }
}

// ---------------------------------------------------------------------------
// x = LayerNorm(x + res) * g + b   (in place). One block (128 thr) / row.
// ---------------------------------------------------------------------------
__global__ __launch_bounds__(128) void add_ln_kernel(
    float* __restrict__ x, const float* __restrict__ res,
    const float* __restrict__ g, const float* __restrict__ bta)
{
    const int row = blockIdx.x;
    const int tid = threadIdx.x;
    float* xr = x + (size_t)row * DD;
    const float* rr = res + (size_t)row * DD;

    float4 xv = ((const float4*)xr)[tid];
    float4 rv = ((const float4*)rr)[tid];
    xv.x += rv.x; xv.y += rv.y; xv.z += rv.z; xv.w += rv.w;

    __shared__ float red1[2];
    __shared__ float red2[2];
    const int lane = tid & 63;
    const int w = tid >> 6;

    float s = xv.x + xv.y + xv.z + xv.w;
#pragma unroll
    for (int off = 32; off > 0; off >>= 1) s += __shfl_xor(s, off);
    if (lane == 0) red1[w] = s;
    __syncthreads();
    const float mean = (red1[0] + red1[1]) * (1.f / (float)DD);

    float d0 = xv.x - mean, d1 = xv.y - mean, d2 = xv.z - mean, d3 = xv.w - mean;
    float sq = d0 * d0 + d1 * d1 + d2 * d2 + d3 * d3;
#pragma unroll
    for (int off = 32; off > 0; off >>= 1) sq += __shfl_xor(sq, off);
    if (lane == 0) red2[w] = sq;
    __syncthreads();
    const float inv = 1.f / sqrtf((red2[0] + red2[1]) * (1.f / (float)DD) + 1e-5f);

    float4 gv = ((const float4*)g)[tid];
    float4 bv = ((const float4*)bta)[tid];
    float4 o;
    o.x = d0 * inv * gv.x + bv.x;
    o.y = d1 * inv * gv.y + bv.y;
    o.z = d2 * inv * gv.z + bv.z;
    o.w = d3 * inv * gv.w + bv.w;
    ((float4*)xr)[tid] = o;
}

// ---------------------------------------------------------------------------
// Row softmax over V=32000, in place. One block (256 thr) per row.
// ---------------------------------------------------------------------------
__global__ __launch_bounds__(256) void softmax_kernel(float* __restrict__ out)
{
    const int row = blockIdx.x;
    float* p = out + (size_t)row * VV;
    const int tid = threadIdx.x;

    float m = -1e30f, s = 0.f;
    for (int j = tid * 4; j < VV; j += 1024) {
        float4 c = *(const float4*)&p[j];
        float lm = fmaxf(fmaxf(c.x, c.y), fmaxf(c.z, c.w));
        if (lm > m) { s *= expf(m - lm); m = lm; }
        s += expf(c.x - m) + expf(c.y - m) + expf(c.z - m) + expf(c.w - m);
    }
#pragma unroll
    for (int off = 32; off > 0; off >>= 1) {
        float mo = __shfl_xor(m, off);
        float so = __shfl_xor(s, off);
        float nm = fmaxf(m, mo);
        s = s * expf(m - nm) + so * expf(mo - nm);
        m = nm;
    }
    __shared__ float ms[4], ss2[4];
    const int lane = tid & 63;
    const int w = tid >> 6;
    if (lane == 0) { ms[w] = m; ss2[w] = s; }
    __syncthreads();
    float fm = fmaxf(fmaxf(ms[0], ms[1]), fmaxf(ms[2], ms[3]));
    float fs = ss2[0] * expf(ms[0] - fm) + ss2[1] * expf(ms[1] - fm) +
               ss2[2] * expf(ms[2] - fm) + ss2[3] * expf(ms[3] - fm);
    const float inv = 1.f / fs;
    for (int j = tid * 4; j < VV; j += 1024) {
        float4 c = *(const float4*)&p[j];
        c.x = expf(c.x - fm) * inv;
        c.y = expf(c.y - fm) * inv;
        c.z = expf(c.z - fm) * inv;
        c.w = expf(c.w - fm) * inv;
        *(float4*)&p[j] = c;
    }
}

// ---------------------------------------------------------------------------
static inline void launch_gemm(const float* A, const float* W, const float* bias,
                               float* C, int M, int N, int K, int relu,
                               hipStream_t st)
{
    dim3 grid(N / 128, (M + 127) / 128);
    gemm_mfma_kernel<<<grid, 256, 0, st>>>(A, W, bias, C, M, N, K, relu);
}

extern "C" void kernel_launch(void* const* d_in, const int* in_sizes, int n_in,
                              void* d_out, int out_size, void* d_ws, size_t ws_size,
                              hipStream_t stream)
{
    const int*   tokens = (const int*)  d_in[0];
    const float* emb    = (const float*)d_in[1];
    const float* wq     = (const float*)d_in[2];
    const float* bq     = (const float*)d_in[3];
    const float* wk     = (const float*)d_in[4];
    const float* bk     = (const float*)d_in[5];
    const float* wv     = (const float*)d_in[6];
    const float* bv     = (const float*)d_in[7];
    const float* wo     = (const float*)d_in[8];
    const float* bo     = (const float*)d_in[9];
    const float* ln1g   = (const float*)d_in[10];
    const float* ln1b   = (const float*)d_in[11];
    const float* w1     = (const float*)d_in[12];
    const float* b1     = (const float*)d_in[13];
    const float* w2     = (const float*)d_in[14];
    const float* b2     = (const float*)d_in[15];
    const float* ln2g   = (const float*)d_in[16];
    const float* ln2b   = (const float*)d_in[17];
    const float* fcw    = (const float*)d_in[18];
    const float* fcb    = (const float*)d_in[19];
    float* out = (float*)d_out;

    const size_t XN = (size_t)MM * DD;        // 2,048,000
    float* x    = (float*)d_ws;
    float* qkv  = x   + XN;                   // [M][1536] fused
    float* ctx  = qkv + 3 * XN;
    float* attn = ctx + XN;
    float* hbuf = out + ((size_t)MM * VV - (size_t)MM * FFD);

    embed_pe_kernel<<<(MM * DD) / 256, 256, 0, stream>>>(tokens, emb, x);

    for (int l = 0; l < LL; l++) {
        const size_t wo2 = (size_t)l * DD * DD;
        gemm_qkv_kernel<<<dim3(12, (MM + 127) / 128), 256, 0, stream>>>(
            x, wq + wo2, wk + wo2, wv + wo2,
            bq + l * DD, bk + l * DD, bv + l * DD, qkv, MM);
        attention_kernel<<<BB * HH * ((SS + QT - 1) / QT), 512, 0, stream>>>(qkv, ctx);
        launch_gemm(ctx, wo + wo2, bo + l * DD, attn, MM, DD, DD, 0, stream);
        add_ln_kernel<<<MM, 128, 0, stream>>>(x, attn, ln1g + l * DD, ln1b + l * DD);
        launch_gemm(x, w1 + (size_t)l * DD * FFD, b1 + l * FFD, hbuf, MM, FFD, DD, 1, stream);
        launch_gemm(hbuf, w2 + (size_t)l * FFD * DD, b2 + l * DD, attn, MM, DD, FFD, 0, stream);
        add_ln_kernel<<<MM, 128, 0, stream>>>(x, attn, ln2g + l * DD, ln2b + l * DD);
    }

    launch_gemm(x, fcw, fcb, out, MM, VV, DD, 0, stream);
    softmax_kernel<<<MM, 256, 0, stream>>>(out);
}

// Round 5
// 2770.303 us; speedup vs baseline: 2.5977x; 1.0620x over previous
//
#include <hip/hip_runtime.h>
#include <math.h>

#define BB 4
#define SS 1000
#define DD 512
#define HH 8
#define HD 64
#define LL 4
#define FFD 2048
#define VV 32000
#define MM (BB*SS)      // 4000
#define QKV_STR 1536    // fused q|k|v row stride

typedef __attribute__((ext_vector_type(8))) short bf16x8;
typedef __attribute__((ext_vector_type(4))) short bf16x4;
typedef __attribute__((ext_vector_type(4))) float f32x4;

// ---------------------------------------------------------------------------
// fp32 -> bf16 (RNE) split helpers: f = hi + lo with |err| ~ 2^-17 * |f|
// ---------------------------------------------------------------------------
__device__ __forceinline__ unsigned short f2bf(float f)
{
    unsigned int u = __float_as_uint(f);
    u += 0x7FFFu + ((u >> 16) & 1u);      // round-to-nearest-even
    return (unsigned short)(u >> 16);
}
__device__ __forceinline__ float bf2f(unsigned short h)
{
    return __uint_as_float((unsigned int)h << 16);
}
__device__ __forceinline__ void split8(const float* f, bf16x8& h8, bf16x8& l8)
{
#pragma unroll
    for (int j = 0; j < 8; j++) {
        unsigned short h = f2bf(f[j]);
        unsigned short l = f2bf(f[j] - bf2f(h));
        h8[j] = (short)h;
        l8[j] = (short)l;
    }
}

// ---------------------------------------------------------------------------
// Embedding + positional encoding -> x fp32 AND x hi/lo bf16 split
// ---------------------------------------------------------------------------
__global__ __launch_bounds__(256) void embed_pe_kernel(
    const int* __restrict__ tokens, const float* __restrict__ emb,
    float* __restrict__ x, unsigned short* __restrict__ xhi,
    unsigned short* __restrict__ xlo)
{
    int idx = blockIdx.x * 256 + threadIdx.x;      // < B*S*D
    int d  = idx & (DD - 1);
    int bs = idx >> 9;
    int s  = bs % SS;
    int tok = tokens[bs];
    float i2 = (float)(d & ~1);
    float dv = expf(i2 * (-9.210340371976184f / (float)DD));
    float ang = (float)s * dv;
    float pe = (d & 1) ? cosf(ang) : sinf(ang);
    float v = emb[(size_t)tok * DD + d] + pe;
    x[idx] = v;
    unsigned short h = f2bf(v);
    xhi[idx] = h;
    xlo[idx] = f2bf(v - bf2f(h));
}

// ---------------------------------------------------------------------------
// Weight transpose + split: W [K][N] fp32 (ld=ldn) -> Wt hi/lo [n0+N][K] ushort
// 32x32 LDS tile transpose. grid = (N/32, K/32).
// ---------------------------------------------------------------------------
__global__ __launch_bounds__(256) void wtconv_kernel(
    const float* __restrict__ W, int ldn,
    unsigned short* __restrict__ thi, unsigned short* __restrict__ tlo,
    int ldk, int n0)
{
    __shared__ unsigned short lh[32][33];
    __shared__ unsigned short ll[32][33];
    const int tid = threadIdx.x;
    const int nn0 = blockIdx.x * 32;
    const int k0  = blockIdx.y * 32;

    {
        const int k = tid >> 3;
        const int n = (tid & 7) * 4;
        float4 v = *(const float4*)&W[(size_t)(k0 + k) * ldn + nn0 + n];
        float fv[4] = {v.x, v.y, v.z, v.w};
#pragma unroll
        for (int i = 0; i < 4; i++) {
            unsigned short h = f2bf(fv[i]);
            lh[k][n + i] = h;
            ll[k][n + i] = f2bf(fv[i] - bf2f(h));
        }
    }
    __syncthreads();
    {
        const int nw = tid >> 3;
        const int kw = (tid & 7) * 4;
        unsigned int h0 = (unsigned int)lh[kw][nw]     | ((unsigned int)lh[kw + 1][nw] << 16);
        unsigned int h1 = (unsigned int)lh[kw + 2][nw] | ((unsigned int)lh[kw + 3][nw] << 16);
        unsigned int l0 = (unsigned int)ll[kw][nw]     | ((unsigned int)ll[kw + 1][nw] << 16);
        unsigned int l1 = (unsigned int)ll[kw + 2][nw] | ((unsigned int)ll[kw + 3][nw] << 16);
        const size_t o = (size_t)(n0 + nn0 + nw) * ldk + k0 + kw;
        *(uint2*)&thi[o] = make_uint2(h0, h1);
        *(uint2*)&tlo[o] = make_uint2(l0, l1);
    }
}

// Concatenate 3 bias vectors of 512 into one 1536 buffer. grid 6 x 256.
__global__ __launch_bounds__(256) void concat_bias_kernel(
    const float* __restrict__ a, const float* __restrict__ b,
    const float* __restrict__ c, float* __restrict__ o)
{
    int t = blockIdx.x * 256 + threadIdx.x;
    if (t < 512) o[t] = a[t];
    else if (t < 1024) o[t] = b[t - 512];
    else if (t < 1536) o[t] = c[t - 1024];
}

// ---------------------------------------------------------------------------
// Templated MFMA GEMM. A pre-split bf16 [M][K]. B either pre-split transposed
// [N][K] bf16 (BF32=false) or fp32 [K][N] converted hi-only on stage (BF32).
// SPLIT=3: hi/lo 3-MFMA (fp32-class accuracy). SPLIT=1: plain bf16, 1 MFMA.
// OSPLIT: write bf16 hi/lo output (for GEMM->GEMM chaining) else fp32.
// 128x128 tile, BK=32, 256 thr, 4 waves x (64x64 via 4x4 16x16x32 frags).
// ---------------------------------------------------------------------------
#define BKP 40

template<int SPLIT, bool BF32, bool OSPLIT>
__global__ __launch_bounds__(256) void gemm_t(
    const unsigned short* __restrict__ Ahi, const unsigned short* __restrict__ Alo,
    const unsigned short* __restrict__ Bth, const unsigned short* __restrict__ Btl,
    const float* __restrict__ Bf, int ldbf,
    const float* __restrict__ bias,
    float* __restrict__ Cf, unsigned short* __restrict__ Chi,
    unsigned short* __restrict__ Clo,
    int M, int K, int ldc, int relu)
{
    __shared__ unsigned short Ah[128][BKP];
    __shared__ unsigned short Al[SPLIT == 3 ? 128 : 1][SPLIT == 3 ? BKP : 1];
    __shared__ unsigned short Bh[128][BKP];
    __shared__ unsigned short Bl[SPLIT == 3 ? 128 : 1][SPLIT == 3 ? BKP : 1];

    const int tid  = threadIdx.x;
    const int lane = tid & 63;
    const int wid  = tid >> 6;
    const int wm   = (wid >> 1) << 6;
    const int wn   = (wid & 1) << 6;
    const int fr   = lane & 15;
    const int ko   = (lane >> 4) << 3;
    const int bm   = blockIdx.y * 128;
    const int bn0  = blockIdx.x * 128;

    f32x4 acc[4][4];
#pragma unroll
    for (int i = 0; i < 4; i++)
#pragma unroll
        for (int j = 0; j < 4; j++)
            acc[i][j] = (f32x4){0.f, 0.f, 0.f, 0.f};

    const uint4 zz = {0u, 0u, 0u, 0u};
    for (int k0 = 0; k0 < K; k0 += 32) {
#pragma unroll
        for (int p = 0; p < 2; p++) {
            const int c   = tid + (p << 8);
            const int row = c >> 2;
            const int ks  = (c & 3) << 3;
            const int gm  = bm + row;
            *(uint4*)&Ah[row][ks] =
                (gm < M) ? *(const uint4*)&Ahi[(size_t)gm * K + k0 + ks] : zz;
            if (SPLIT == 3)
                *(uint4*)&Al[row][ks] =
                    (gm < M) ? *(const uint4*)&Alo[(size_t)gm * K + k0 + ks] : zz;
            if (!BF32) {
                *(uint4*)&Bh[row][ks] = *(const uint4*)&Bth[(size_t)(bn0 + row) * K + k0 + ks];
                if (SPLIT == 3)
                    *(uint4*)&Bl[row][ks] = *(const uint4*)&Btl[(size_t)(bn0 + row) * K + k0 + ks];
            }
        }
        if (BF32) {
#pragma unroll
            for (int u = 0; u < 2; u++) {
                const int n   = (tid & 63) + (u << 6);
                const int bkk = (tid >> 6) << 3;
                const float* wp = &Bf[(size_t)(k0 + bkk) * ldbf + bn0 + n];
                unsigned int hp[4];
#pragma unroll
                for (int i = 0; i < 4; i++) {
                    unsigned short h0 = f2bf(wp[(size_t)(2 * i) * ldbf]);
                    unsigned short h1 = f2bf(wp[(size_t)(2 * i + 1) * ldbf]);
                    hp[i] = (unsigned int)h0 | ((unsigned int)h1 << 16);
                }
                *(uint4*)&Bh[n][bkk] = make_uint4(hp[0], hp[1], hp[2], hp[3]);
            }
        }
        __syncthreads();

        bf16x8 ah[4], bh[4], al[4], bl[4];
#pragma unroll
        for (int i = 0; i < 4; i++) {
            ah[i] = *(const bf16x8*)&Ah[wm + i * 16 + fr][ko];
            if (SPLIT == 3) al[i] = *(const bf16x8*)&Al[wm + i * 16 + fr][ko];
        }
#pragma unroll
        for (int j = 0; j < 4; j++) {
            bh[j] = *(const bf16x8*)&Bh[wn + j * 16 + fr][ko];
            if (SPLIT == 3) bl[j] = *(const bf16x8*)&Bl[wn + j * 16 + fr][ko];
        }
#pragma unroll
        for (int i = 0; i < 4; i++)
#pragma unroll
            for (int j = 0; j < 4; j++) {
                acc[i][j] = __builtin_amdgcn_mfma_f32_16x16x32_bf16(ah[i], bh[j], acc[i][j], 0, 0, 0);
                if (SPLIT == 3) {
                    acc[i][j] = __builtin_amdgcn_mfma_f32_16x16x32_bf16(ah[i], bl[j], acc[i][j], 0, 0, 0);
                    acc[i][j] = __builtin_amdgcn_mfma_f32_16x16x32_bf16(al[i], bh[j], acc[i][j], 0, 0, 0);
                }
            }
        __syncthreads();
    }

    // epilogue: D[row=(lane>>4)*4+r][col=lane&15] (harness-verified mapping)
    const int cr = (lane >> 4) << 2;
    const int cc = lane & 15;
#pragma unroll
    for (int j = 0; j < 4; j++) {
        const int lc  = wn + j * 16 + cc;
        const float bv = bias[bn0 + lc];
        const int col = bn0 + lc;
#pragma unroll
        for (int i = 0; i < 4; i++) {
            f32x4 a = acc[i][j];
#pragma unroll
            for (int r = 0; r < 4; r++) {
                const int row = bm + wm + i * 16 + cr + r;
                if (row < M) {
                    float v = a[r] + bv;
                    if (relu) v = fmaxf(v, 0.f);
                    if (OSPLIT) {
                        unsigned short h = f2bf(v);
                        Chi[(size_t)row * ldc + col] = h;
                        Clo[(size_t)row * ldc + col] = f2bf(v - bf2f(h));
                    } else {
                        Cf[(size_t)row * ldc + col] = v;
                    }
                }
            }
        }
    }
}

// ---------------------------------------------------------------------------
// Flash-style MFMA attention, consuming pre-split qkv (hi/lo [M][1536]).
// Scale 1/8 folded post-MFMA. Emits ctx as bf16 hi/lo split for O-proj GEMM.
// ---------------------------------------------------------------------------
#define QT 128
#define KVT 64
#define KP 72
#define VP 72

__device__ __forceinline__ bf16x8 ld_pair(const unsigned short* p0,
                                          const unsigned short* p1)
{
    union { bf16x8 v; bf16x4 q[2]; } u;
    u.q[0] = *(const bf16x4*)p0;
    u.q[1] = *(const bf16x4*)p1;
    return u.v;
}

__global__ __launch_bounds__(512) void attention_kernel(
    const unsigned short* __restrict__ qvh, const unsigned short* __restrict__ qvl,
    unsigned short* __restrict__ chi, unsigned short* __restrict__ clo)
{
    __shared__ __align__(16) unsigned short Kh[KVT][KP];
    __shared__ __align__(16) unsigned short Kl[KVT][KP];
    __shared__ __align__(16) unsigned short Vth[HD][VP];
    __shared__ __align__(16) unsigned short Vtl[HD][VP];

    const int tid  = threadIdx.x;
    const int lane = tid & 63;
    const int w    = tid >> 6;
    const int r16  = lane & 15;
    const int g    = lane >> 4;

    const int nqt = (SS + QT - 1) / QT;          // 8
    const int qt  = blockIdx.x % nqt;
    const int bh  = blockIdx.x / nqt;
    const int h   = bh % HH;
    const int b   = bh / HH;
    const int q0  = qt * QT;

    const size_t base = (size_t)b * SS * QKV_STR + (size_t)h * HD;

    // ---- Q fragments straight from pre-split global ----------------------
    const int qrow = q0 + w * 16 + r16;
    const int qr   = qrow < SS ? qrow : SS - 1;
    const unsigned short* qph = qvh + base + (size_t)qr * QKV_STR;
    const unsigned short* qpl = qvl + base + (size_t)qr * QKV_STR;
    bf16x8 qh[2], ql[2];
#pragma unroll
    for (int c = 0; c < 2; c++) {
        qh[c] = ld_pair(&qph[c * 32 + g * 4], &qph[c * 32 + 16 + g * 4]);
        ql[c] = ld_pair(&qpl[c * 32 + g * 4], &qpl[c * 32 + 16 + g * 4]);
    }

    f32x4 oacc[4];
#pragma unroll
    for (int f = 0; f < 4; f++) oacc[f] = (f32x4){0.f, 0.f, 0.f, 0.f};
    float mrow = -1e30f, lrow = 0.f;

    const uint4 zz = {0u, 0u, 0u, 0u};
    const int ntiles = (SS + KVT - 1) / KVT;     // 16
    for (int t = 0; t < ntiles; t++) {
        const int kv0 = t * KVT;
        __syncthreads();
        // ---- stage K tile [kj][d]: pure uint4 copy -----------------------
        {
            const int kj   = tid >> 3;
            const int dblk = (tid & 7) * 8;
            const int krow = kv0 + kj;
            if (krow < SS) {
                const size_t o = base + (size_t)krow * QKV_STR + DD + dblk;
                *(uint4*)&Kh[kj][dblk] = *(const uint4*)&qvh[o];
                *(uint4*)&Kl[kj][dblk] = *(const uint4*)&qvl[o];
            } else {
                *(uint4*)&Kh[kj][dblk] = zz;
                *(uint4*)&Kl[kj][dblk] = zz;
            }
        }
        // ---- stage V tile transposed Vt[d][kj]: copy + scatter -----------
        {
            const int kj = tid & 63;
            const int d0 = (tid >> 6) * 8;
            const int vrow = kv0 + kj;
            union { uint4 u; unsigned short s[8]; } vh4, vl4;
            if (vrow < SS) {
                const size_t o = base + (size_t)vrow * QKV_STR + 2 * DD + d0;
                vh4.u = *(const uint4*)&qvh[o];
                vl4.u = *(const uint4*)&qvl[o];
            } else {
                vh4.u = zz; vl4.u = zz;
            }
#pragma unroll
            for (int i = 0; i < 8; i++) {
                Vth[d0 + i][kj] = vh4.s[i];
                Vtl[d0 + i][kj] = vl4.s[i];
            }
        }
        __syncthreads();

        // ---- S^T = K·Q^T (3-term split) ----------------------------------
        f32x4 sac[4];
#pragma unroll
        for (int f = 0; f < 4; f++) sac[f] = (f32x4){0.f, 0.f, 0.f, 0.f};
#pragma unroll
        for (int f = 0; f < 4; f++) {
            const int ar = f * 16 + r16;
#pragma unroll
            for (int c = 0; c < 2; c++) {
                bf16x8 ah = ld_pair(&Kh[ar][c * 32 + g * 4], &Kh[ar][c * 32 + 16 + g * 4]);
                bf16x8 al = ld_pair(&Kl[ar][c * 32 + g * 4], &Kl[ar][c * 32 + 16 + g * 4]);
                sac[f] = __builtin_amdgcn_mfma_f32_16x16x32_bf16(ah, qh[c], sac[f], 0, 0, 0);
                sac[f] = __builtin_amdgcn_mfma_f32_16x16x32_bf16(ah, ql[c], sac[f], 0, 0, 0);
                sac[f] = __builtin_amdgcn_mfma_f32_16x16x32_bf16(al, qh[c], sac[f], 0, 0, 0);
            }
        }
        // scale (1/sqrt(64)) folded here instead of into Q
#pragma unroll
        for (int f = 0; f < 4; f++)
#pragma unroll
            for (int rr = 0; rr < 4; rr++) sac[f][rr] *= 0.125f;
        // mask tail kj
        if (kv0 + KVT > SS) {
#pragma unroll
            for (int f = 0; f < 4; f++)
#pragma unroll
                for (int rr = 0; rr < 4; rr++)
                    if (kv0 + f * 16 + g * 4 + rr >= SS) sac[f][rr] = -1e30f;
        }

        // ---- online softmax (per qi = lane&15, replicated over g) --------
        float tmax = -1e30f;
#pragma unroll
        for (int f = 0; f < 4; f++)
#pragma unroll
            for (int rr = 0; rr < 4; rr++) tmax = fmaxf(tmax, sac[f][rr]);
        tmax = fmaxf(tmax, __shfl_xor(tmax, 16));
        tmax = fmaxf(tmax, __shfl_xor(tmax, 32));
        const float mnew = fmaxf(mrow, tmax);
        const float scal = __expf(mrow - mnew);
        mrow = mnew;
        float tsum = 0.f;
#pragma unroll
        for (int f = 0; f < 4; f++)
#pragma unroll
            for (int rr = 0; rr < 4; rr++) {
                float e = __expf(sac[f][rr] - mnew);
                sac[f][rr] = e;
                tsum += e;
            }
        tsum += __shfl_xor(tsum, 16);
        tsum += __shfl_xor(tsum, 32);
        lrow = lrow * scal + tsum;
#pragma unroll
        for (int f = 0; f < 4; f++) {
            oacc[f][0] *= scal; oacc[f][1] *= scal;
            oacc[f][2] *= scal; oacc[f][3] *= scal;
        }

        // ---- P -> bf16 hi/lo B-fragments (pure reg) ----------------------
        bf16x8 ph[2], pl[2];
#pragma unroll
        for (int c = 0; c < 2; c++) {
            float pv[8] = {sac[2 * c][0], sac[2 * c][1], sac[2 * c][2], sac[2 * c][3],
                           sac[2 * c + 1][0], sac[2 * c + 1][1], sac[2 * c + 1][2], sac[2 * c + 1][3]};
            split8(pv, ph[c], pl[c]);
        }

        // ---- O^T += V^T · P^T --------------------------------------------
#pragma unroll
        for (int f = 0; f < 4; f++) {
            const int ar = f * 16 + r16;
#pragma unroll
            for (int c = 0; c < 2; c++) {
                bf16x8 vh = ld_pair(&Vth[ar][c * 32 + g * 4], &Vth[ar][c * 32 + 16 + g * 4]);
                bf16x8 vl = ld_pair(&Vtl[ar][c * 32 + g * 4], &Vtl[ar][c * 32 + 16 + g * 4]);
                oacc[f] = __builtin_amdgcn_mfma_f32_16x16x32_bf16(vh, ph[c], oacc[f], 0, 0, 0);
                oacc[f] = __builtin_amdgcn_mfma_f32_16x16x32_bf16(vh, pl[c], oacc[f], 0, 0, 0);
                oacc[f] = __builtin_amdgcn_mfma_f32_16x16x32_bf16(vl, ph[c], oacc[f], 0, 0, 0);
            }
        }
    }

    // ---- epilogue: ctx split hi/lo (O-proj GEMM consumes it) -------------
    if (qrow < SS) {
        const float inv = 1.f / lrow;
        const size_t ci = ((size_t)b * SS + qrow) * DD + (size_t)h * HD;
#pragma unroll
        for (int f = 0; f < 4; f++) {
            unsigned short hs[4], ls[4];
#pragma unroll
            for (int r = 0; r < 4; r++) {
                float v = oacc[f][r] * inv;
                hs[r] = f2bf(v);
                ls[r] = f2bf(v - bf2f(hs[r]));
            }
            unsigned int h0 = (unsigned int)hs[0] | ((unsigned int)hs[1] << 16);
            unsigned int h1 = (unsigned int)hs[2] | ((unsigned int)hs[3] << 16);
            unsigned int l0 = (unsigned int)ls[0] | ((unsigned int)ls[1] << 16);
            unsigned int l1 = (unsigned int)ls[2] | ((unsigned int)ls[3] << 16);
            *(uint2*)&chi[ci + f * 16 + g * 4] = make_uint2(h0, h1);
            *(uint2*)&clo[ci + f * 16 + g * 4] = make_uint2(l0, l1);
        }
    }
}

// ---------------------------------------------------------------------------
// x = LayerNorm(x + res) * g + b (in place) + emit x bf16 hi/lo split.
// ---------------------------------------------------------------------------
__global__ __launch_bounds__(128) void add_ln_kernel(
    float* __restrict__ x, const float* __restrict__ res,
    const float* __restrict__ g, const float* __restrict__ bta,
    unsigned short* __restrict__ xhi, unsigned short* __restrict__ xlo)
{
    const int row = blockIdx.x;
    const int tid = threadIdx.x;
    float* xr = x + (size_t)row * DD;
    const float* rr = res + (size_t)row * DD;

    float4 xv = ((const float4*)xr)[tid];
    float4 rv = ((const float4*)rr)[tid];
    xv.x += rv.x; xv.y += rv.y; xv.z += rv.z; xv.w += rv.w;

    __shared__ float red1[2];
    __shared__ float red2[2];
    const int lane = tid & 63;
    const int w = tid >> 6;

    float s = xv.x + xv.y + xv.z + xv.w;
#pragma unroll
    for (int off = 32; off > 0; off >>= 1) s += __shfl_xor(s, off);
    if (lane == 0) red1[w] = s;
    __syncthreads();
    const float mean = (red1[0] + red1[1]) * (1.f / (float)DD);

    float d0 = xv.x - mean, d1 = xv.y - mean, d2 = xv.z - mean, d3 = xv.w - mean;
    float sq = d0 * d0 + d1 * d1 + d2 * d2 + d3 * d3;
#pragma unroll
    for (int off = 32; off > 0; off >>= 1) sq += __shfl_xor(sq, off);
    if (lane == 0) red2[w] = sq;
    __syncthreads();
    const float inv = 1.f / sqrtf((red2[0] + red2[1]) * (1.f / (float)DD) + 1e-5f);

    float4 gv = ((const float4*)g)[tid];
    float4 bv = ((const float4*)bta)[tid];
    float4 o;
    o.x = d0 * inv * gv.x + bv.x;
    o.y = d1 * inv * gv.y + bv.y;
    o.z = d2 * inv * gv.z + bv.z;
    o.w = d3 * inv * gv.w + bv.w;
    ((float4*)xr)[tid] = o;

    unsigned short h0 = f2bf(o.x), h1 = f2bf(o.y), h2 = f2bf(o.z), h3 = f2bf(o.w);
    unsigned short l0 = f2bf(o.x - bf2f(h0)), l1 = f2bf(o.y - bf2f(h1));
    unsigned short l2 = f2bf(o.z - bf2f(h2)), l3 = f2bf(o.w - bf2f(h3));
    const size_t oidx = (size_t)row * DD + tid * 4;
    *(uint2*)&xhi[oidx] = make_uint2((unsigned int)h0 | ((unsigned int)h1 << 16),
                                     (unsigned int)h2 | ((unsigned int)h3 << 16));
    *(uint2*)&xlo[oidx] = make_uint2((unsigned int)l0 | ((unsigned int)l1 << 16),
                                     (unsigned int)l2 | ((unsigned int)l3 << 16));
}

// ---------------------------------------------------------------------------
// Row softmax over V=32000, in place. One block (256 thr) per row.
// ---------------------------------------------------------------------------
__global__ __launch_bounds__(256) void softmax_kernel(float* __restrict__ out)
{
    const int row = blockIdx.x;
    float* p = out + (size_t)row * VV;
    const int tid = threadIdx.x;

    float m = -1e30f, s = 0.f;
    for (int j = tid * 4; j < VV; j += 1024) {
        float4 c = *(const float4*)&p[j];
        float lm = fmaxf(fmaxf(c.x, c.y), fmaxf(c.z, c.w));
        if (lm > m) { s *= expf(m - lm); m = lm; }
        s += expf(c.x - m) + expf(c.y - m) + expf(c.z - m) + expf(c.w - m);
    }
#pragma unroll
    for (int off = 32; off > 0; off >>= 1) {
        float mo = __shfl_xor(m, off);
        float so = __shfl_xor(s, off);
        float nm = fmaxf(m, mo);
        s = s * expf(m - nm) + so * expf(mo - nm);
        m = nm;
    }
    __shared__ float ms[4], ss2[4];
    const int lane = tid & 63;
    const int w = tid >> 6;
    if (lane == 0) { ms[w] = m; ss2[w] = s; }
    __syncthreads();
    float fm = fmaxf(fmaxf(ms[0], ms[1]), fmaxf(ms[2], ms[3]));
    float fs = ss2[0] * expf(ms[0] - fm) + ss2[1] * expf(ms[1] - fm) +
               ss2[2] * expf(ms[2] - fm) + ss2[3] * expf(ms[3] - fm);
    const float inv = 1.f / fs;
    for (int j = tid * 4; j < VV; j += 1024) {
        float4 c = *(const float4*)&p[j];
        c.x = expf(c.x - fm) * inv;
        c.y = expf(c.y - fm) * inv;
        c.z = expf(c.z - fm) * inv;
        c.w = expf(c.w - fm) * inv;
        *(float4*)&p[j] = c;
    }
}

// ---------------------------------------------------------------------------
extern "C" void kernel_launch(void* const* d_in, const int* in_sizes, int n_in,
                              void* d_out, int out_size, void* d_ws, size_t ws_size,
                              hipStream_t stream)
{
    const int*   tokens = (const int*)  d_in[0];
    const float* emb    = (const float*)d_in[1];
    const float* wq     = (const float*)d_in[2];
    const float* bq     = (const float*)d_in[3];
    const float* wk     = (const float*)d_in[4];
    const float* bk     = (const float*)d_in[5];
    const float* wv     = (const float*)d_in[6];
    const float* bv     = (const float*)d_in[7];
    const float* wo     = (const float*)d_in[8];
    const float* bo     = (const float*)d_in[9];
    const float* ln1g   = (const float*)d_in[10];
    const float* ln1b   = (const float*)d_in[11];
    const float* w1     = (const float*)d_in[12];
    const float* b1     = (const float*)d_in[13];
    const float* w2     = (const float*)d_in[14];
    const float* b2     = (const float*)d_in[15];
    const float* ln2g   = (const float*)d_in[16];
    const float* ln2b   = (const float*)d_in[17];
    const float* fcw    = (const float*)d_in[18];
    const float* fcb    = (const float*)d_in[19];
    float* out = (float*)d_out;

    const size_t XN = (size_t)MM * DD;        // 2,048,000
    float* ws = (float*)d_ws;
    // ws map (exactly 6*XN floats = same footprint as previous rounds):
    float* x = ws;                                            // [0, XN)
    unsigned short* xhi = (unsigned short*)(ws + XN);         // XN ushorts
    unsigned short* xlo = xhi + XN;                           // ends at ws+2XN
    unsigned short* qkvhi = (unsigned short*)(ws + 2 * XN);   // 3*XN ushorts
    unsigned short* qkvlo = qkvhi + 3 * XN;                   // ends at ws+5XN
    float* attn = ws + 5 * XN;                                // [5XN, 6XN)

    // out tail (32.77 MB; dead until each use, fully dead before FC writes):
    unsigned short* tailu = (unsigned short*)(out + ((size_t)MM * VV - (size_t)MM * FFD));
    unsigned short* ctxhi = tailu;                 // XN ushorts (attn->O window)
    unsigned short* ctxlo = tailu + XN;
    unsigned short* Hhi   = tailu;                 // MM*FFD ushorts (FFN window)
    unsigned short* Hlo   = tailu + (size_t)MM * FFD;

    // weight-transpose scratch in qkv region (dead outside QKV gemm/attention)
    unsigned short* wth = qkvhi;
    unsigned short* wtl = qkvhi + 1048576;         // max 512x2048 elems
    // QKV weight scratch + fused bias in attn region (dead during QKV gemm)
    unsigned short* qwth = (unsigned short*)attn;  // 1536*512 = 786432 elems
    unsigned short* qwtl = qwth + 786432;
    float* biasc = (float*)(qwtl + 786432);        // 1536 floats

    embed_pe_kernel<<<(MM * DD) / 256, 256, 0, stream>>>(tokens, emb, x, xhi, xlo);

    for (int l = 0; l < LL; l++) {
        const size_t wo2 = (size_t)l * DD * DD;
        // ---- QKV (fused N=1536) ----
        concat_bias_kernel<<<6, 256, 0, stream>>>(bq + l * DD, bk + l * DD, bv + l * DD, biasc);
        wtconv_kernel<<<dim3(16, 16), 256, 0, stream>>>(wq + wo2, DD, qwth, qwtl, DD, 0);
        wtconv_kernel<<<dim3(16, 16), 256, 0, stream>>>(wk + wo2, DD, qwth, qwtl, DD, 512);
        wtconv_kernel<<<dim3(16, 16), 256, 0, stream>>>(wv + wo2, DD, qwth, qwtl, DD, 1024);
        gemm_t<3, false, true><<<dim3(12, 32), 256, 0, stream>>>(
            xhi, xlo, qwth, qwtl, nullptr, 0, biasc,
            nullptr, qkvhi, qkvlo, MM, DD, QKV_STR, 0);
        // ---- attention ----
        attention_kernel<<<BB * HH * ((SS + QT - 1) / QT), 512, 0, stream>>>(
            qkvhi, qkvlo, ctxhi, ctxlo);
        // ---- O projection ----
        wtconv_kernel<<<dim3(16, 16), 256, 0, stream>>>(wo + wo2, DD, wth, wtl, DD, 0);
        gemm_t<3, false, false><<<dim3(4, 32), 256, 0, stream>>>(
            ctxhi, ctxlo, wth, wtl, nullptr, 0, bo + l * DD,
            attn, nullptr, nullptr, MM, DD, DD, 0);
        add_ln_kernel<<<MM, 128, 0, stream>>>(x, attn, ln1g + l * DD, ln1b + l * DD, xhi, xlo);
        // ---- FFN1 (relu, split output) ----
        wtconv_kernel<<<dim3(64, 16), 256, 0, stream>>>(w1 + (size_t)l * DD * FFD, FFD, wth, wtl, DD, 0);
        gemm_t<3, false, true><<<dim3(16, 32), 256, 0, stream>>>(
            xhi, xlo, wth, wtl, nullptr, 0, b1 + l * FFD,
            nullptr, Hhi, Hlo, MM, DD, FFD, 1);
        // ---- FFN2 ----
        wtconv_kernel<<<dim3(16, 64), 256, 0, stream>>>(w2 + (size_t)l * FFD * DD, DD, wth, wtl, FFD, 0);
        gemm_t<3, false, false><<<dim3(4, 32), 256, 0, stream>>>(
            Hhi, Hlo, wth, wtl, nullptr, 0, b2 + l * DD,
            attn, nullptr, nullptr, MM, FFD, DD, 0);
        add_ln_kernel<<<MM, 128, 0, stream>>>(x, attn, ln2g + l * DD, ln2b + l * DD, xhi, xlo);
    }

    // ---- final FC: plain bf16 (softmax crushes logit error), B on-the-fly -
    gemm_t<1, true, false><<<dim3(VV / 128, 32), 256, 0, stream>>>(
        xhi, nullptr, nullptr, nullptr, fcw, VV, fcb,
        out, nullptr, nullptr, MM, DD, VV, 0);
    softmax_kernel<<<MM, 256, 0, stream>>>(out);
}